// Round 1
// baseline (452.985 us; speedup 1.0000x reference)
//
#include <hip/hip_runtime.h>

// ReactionTerm: y_out[b, inds_1p[i]] += y_in[b, inds_1r[i]] * rate_1[b,i]
//               y_out[b, inds_2p[j]] += y_in[b, r0[j]] * y_in[b, r1[j]] * rate_2[b,j]
// B=4096, S=1024, N1=4096, N2=16384 (derived from in_sizes at launch).
//
// Memory-bound: ~352 MB HBM traffic/call. One block per batch row; y-row and
// accumulator row live in LDS (4 KB each); scatter-add via LDS float atomics.

template <int BLOCK>
__global__ __launch_bounds__(BLOCK) void reaction_kernel(
    const float* __restrict__ y_in,
    const float* __restrict__ rate_1,
    const float* __restrict__ rate_2,
    const int* __restrict__ inds_1r,
    const int* __restrict__ inds_1p,
    const int* __restrict__ inds_2r,   // [N2][2]
    const int* __restrict__ inds_2p,
    float* __restrict__ y_out,
    int S, int N1, int N2)
{
    extern __shared__ float smem[];
    float* y_s = smem;       // [S] staged input row
    float* acc = smem + S;   // [S] output accumulator

    const int b   = blockIdx.x;
    const int tid = threadIdx.x;

    const float* __restrict__ yrow = y_in + (size_t)b * S;

    // Stage y row + zero accumulator (vectorized where S allows).
    int Sv = S & ~3;  // multiple-of-4 part
    for (int i = tid * 4; i < Sv; i += BLOCK * 4) {
        float4 v = *reinterpret_cast<const float4*>(yrow + i);
        *reinterpret_cast<float4*>(y_s + i) = v;
        *reinterpret_cast<float4*>(acc + i) = make_float4(0.f, 0.f, 0.f, 0.f);
    }
    for (int i = Sv + tid; i < S; i += BLOCK) { y_s[i] = yrow[i]; acc[i] = 0.f; }
    __syncthreads();

    // ---- First-order terms ----
    const float* __restrict__ r1 = rate_1 + (size_t)b * N1;
    int N1v = N1 & ~3;
    for (int i = tid * 4; i < N1v; i += BLOCK * 4) {
        float4 r  = *reinterpret_cast<const float4*>(r1 + i);
        int4   ir = *reinterpret_cast<const int4*>(inds_1r + i);
        int4   ip = *reinterpret_cast<const int4*>(inds_1p + i);
        atomicAdd(&acc[ip.x], y_s[ir.x] * r.x);
        atomicAdd(&acc[ip.y], y_s[ir.y] * r.y);
        atomicAdd(&acc[ip.z], y_s[ir.z] * r.z);
        atomicAdd(&acc[ip.w], y_s[ir.w] * r.w);
    }
    for (int i = N1v + tid; i < N1; i += BLOCK) {
        atomicAdd(&acc[inds_1p[i]], y_s[inds_1r[i]] * r1[i]);
    }

    // ---- Second-order terms ----
    const float* __restrict__ r2 = rate_2 + (size_t)b * N2;
    int N2v = N2 & ~3;
    for (int i = tid * 4; i < N2v; i += BLOCK * 4) {
        float4 r  = *reinterpret_cast<const float4*>(r2 + i);
        int4   p0 = *reinterpret_cast<const int4*>(inds_2r + 2 * i);      // pairs i, i+1
        int4   p1 = *reinterpret_cast<const int4*>(inds_2r + 2 * i + 4);  // pairs i+2, i+3
        int4   ip = *reinterpret_cast<const int4*>(inds_2p + i);
        atomicAdd(&acc[ip.x], y_s[p0.x] * y_s[p0.y] * r.x);
        atomicAdd(&acc[ip.y], y_s[p0.z] * y_s[p0.w] * r.y);
        atomicAdd(&acc[ip.z], y_s[p1.x] * y_s[p1.y] * r.z);
        atomicAdd(&acc[ip.w], y_s[p1.z] * y_s[p1.w] * r.w);
    }
    for (int i = N2v + tid; i < N2; i += BLOCK) {
        atomicAdd(&acc[inds_2p[i]],
                  y_s[inds_2r[2 * i]] * y_s[inds_2r[2 * i + 1]] * r2[i]);
    }

    __syncthreads();

    // ---- Write out the row (coalesced float4) ----
    float* __restrict__ orow = y_out + (size_t)b * S;
    for (int i = tid * 4; i < Sv; i += BLOCK * 4) {
        *reinterpret_cast<float4*>(orow + i) = *reinterpret_cast<const float4*>(acc + i);
    }
    for (int i = Sv + tid; i < S; i += BLOCK) orow[i] = acc[i];
}

extern "C" void kernel_launch(void* const* d_in, const int* in_sizes, int n_in,
                              void* d_out, int out_size, void* d_ws, size_t ws_size,
                              hipStream_t stream) {
    const float* y_in    = (const float*)d_in[0];
    const float* rate_1  = (const float*)d_in[1];
    const float* rate_2  = (const float*)d_in[2];
    const int*   inds_1r = (const int*)d_in[3];
    const int*   inds_1p = (const int*)d_in[4];
    const int*   inds_2r = (const int*)d_in[5];
    const int*   inds_2p = (const int*)d_in[6];
    float*       y_out   = (float*)d_out;

    const int N1 = in_sizes[3];           // 4096
    const int N2 = in_sizes[6];           // 16384
    const int B  = in_sizes[1] / N1;      // 4096
    const int S  = in_sizes[0] / B;       // 1024

    constexpr int BLOCK = 256;
    size_t smem = (size_t)2 * S * sizeof(float);  // y row + accumulator row

    reaction_kernel<BLOCK><<<B, BLOCK, smem, stream>>>(
        y_in, rate_1, rate_2, inds_1r, inds_1p, inds_2r, inds_2p,
        y_out, S, N1, N2);
}

// Round 2
// 450.528 us; speedup vs baseline: 1.0055x; 1.0055x over previous
//
#include <hip/hip_runtime.h>

// ReactionTerm: y_out[b, inds_1p[i]] += y_in[b, inds_1r[i]] * rate_1[b,i]
//               y_out[b, inds_2p[j]] += y_in[b, r0[j]] * y_in[b, r1[j]] * rate_2[b,j]
// B=4096, S=1024, N1=4096, N2=16384 (derived from in_sizes at launch).
//
// Memory-bound: ~350 MB HBM traffic/call. One block per batch row; y-row and
// accumulator row live in LDS (4 KB each).
//
// R2 change: LDS scatter-add uses unsafeAtomicAdd -> native ds_add_f32.
// Plain atomicAdd(float*) on AMD compiles to a CAS retry loop (denorm-safe
// path), which serialized the whole kernel in R1 (VALUBusy 3%, HBM 5%).

template <int BLOCK>
__global__ __launch_bounds__(BLOCK) void reaction_kernel(
    const float* __restrict__ y_in,
    const float* __restrict__ rate_1,
    const float* __restrict__ rate_2,
    const int* __restrict__ inds_1r,
    const int* __restrict__ inds_1p,
    const int* __restrict__ inds_2r,   // [N2][2]
    const int* __restrict__ inds_2p,
    float* __restrict__ y_out,
    int S, int N1, int N2)
{
    extern __shared__ float smem[];
    float* y_s = smem;       // [S] staged input row
    float* acc = smem + S;   // [S] output accumulator

    const int b   = blockIdx.x;
    const int tid = threadIdx.x;

    const float* __restrict__ yrow = y_in + (size_t)b * S;

    // Stage y row + zero accumulator (vectorized where S allows).
    int Sv = S & ~3;  // multiple-of-4 part
    for (int i = tid * 4; i < Sv; i += BLOCK * 4) {
        float4 v = *reinterpret_cast<const float4*>(yrow + i);
        *reinterpret_cast<float4*>(y_s + i) = v;
        *reinterpret_cast<float4*>(acc + i) = make_float4(0.f, 0.f, 0.f, 0.f);
    }
    for (int i = Sv + tid; i < S; i += BLOCK) { y_s[i] = yrow[i]; acc[i] = 0.f; }
    __syncthreads();

    // ---- First-order terms ----
    const float* __restrict__ r1 = rate_1 + (size_t)b * N1;
    int N1v = N1 & ~3;
    for (int i = tid * 4; i < N1v; i += BLOCK * 4) {
        float4 r  = *reinterpret_cast<const float4*>(r1 + i);
        int4   ir = *reinterpret_cast<const int4*>(inds_1r + i);
        int4   ip = *reinterpret_cast<const int4*>(inds_1p + i);
        unsafeAtomicAdd(&acc[ip.x], y_s[ir.x] * r.x);
        unsafeAtomicAdd(&acc[ip.y], y_s[ir.y] * r.y);
        unsafeAtomicAdd(&acc[ip.z], y_s[ir.z] * r.z);
        unsafeAtomicAdd(&acc[ip.w], y_s[ir.w] * r.w);
    }
    for (int i = N1v + tid; i < N1; i += BLOCK) {
        unsafeAtomicAdd(&acc[inds_1p[i]], y_s[inds_1r[i]] * r1[i]);
    }

    // ---- Second-order terms ----
    const float* __restrict__ r2 = rate_2 + (size_t)b * N2;
    int N2v = N2 & ~3;
    for (int i = tid * 4; i < N2v; i += BLOCK * 4) {
        float4 r  = *reinterpret_cast<const float4*>(r2 + i);
        int4   p0 = *reinterpret_cast<const int4*>(inds_2r + 2 * i);      // pairs i, i+1
        int4   p1 = *reinterpret_cast<const int4*>(inds_2r + 2 * i + 4);  // pairs i+2, i+3
        int4   ip = *reinterpret_cast<const int4*>(inds_2p + i);
        unsafeAtomicAdd(&acc[ip.x], y_s[p0.x] * y_s[p0.y] * r.x);
        unsafeAtomicAdd(&acc[ip.y], y_s[p0.z] * y_s[p0.w] * r.y);
        unsafeAtomicAdd(&acc[ip.z], y_s[p1.x] * y_s[p1.y] * r.z);
        unsafeAtomicAdd(&acc[ip.w], y_s[p1.z] * y_s[p1.w] * r.w);
    }
    for (int i = N2v + tid; i < N2; i += BLOCK) {
        unsafeAtomicAdd(&acc[inds_2p[i]],
                        y_s[inds_2r[2 * i]] * y_s[inds_2r[2 * i + 1]] * r2[i]);
    }

    __syncthreads();

    // ---- Write out the row (coalesced float4) ----
    float* __restrict__ orow = y_out + (size_t)b * S;
    for (int i = tid * 4; i < Sv; i += BLOCK * 4) {
        *reinterpret_cast<float4*>(orow + i) = *reinterpret_cast<const float4*>(acc + i);
    }
    for (int i = Sv + tid; i < S; i += BLOCK) orow[i] = acc[i];
}

extern "C" void kernel_launch(void* const* d_in, const int* in_sizes, int n_in,
                              void* d_out, int out_size, void* d_ws, size_t ws_size,
                              hipStream_t stream) {
    const float* y_in    = (const float*)d_in[0];
    const float* rate_1  = (const float*)d_in[1];
    const float* rate_2  = (const float*)d_in[2];
    const int*   inds_1r = (const int*)d_in[3];
    const int*   inds_1p = (const int*)d_in[4];
    const int*   inds_2r = (const int*)d_in[5];
    const int*   inds_2p = (const int*)d_in[6];
    float*       y_out   = (float*)d_out;

    const int N1 = in_sizes[3];           // 4096
    const int N2 = in_sizes[6];           // 16384
    const int B  = in_sizes[1] / N1;      // 4096
    const int S  = in_sizes[0] / B;       // 1024

    constexpr int BLOCK = 256;
    size_t smem = (size_t)2 * S * sizeof(float);  // y row + accumulator row

    reaction_kernel<BLOCK><<<B, BLOCK, smem, stream>>>(
        y_in, rate_1, rate_2, inds_1r, inds_1p, inds_2r, inds_2p,
        y_out, S, N1, N2);
}

// Round 3
// 249.877 us; speedup vs baseline: 1.8128x; 1.8030x over previous
//
#include <hip/hip_runtime.h>

// ReactionTerm, gather formulation.
// R1/R2 showed the LDS-atomic scatter serializes (458us with all pipes idle).
// R3: per-call setup builds a sort-by-product-slot CSR (row-invariant indices),
// main kernel gathers per-slot segments from LDS into register accumulators.
// No atomics anywhere in the hot loop.
//
// Fixed problem geometry: B=4096, S=1024, N1=4096, N2=16384.

#define BT 1024

// ---------- K1: histogram of product slots (global int atomics) ----------
__global__ void hist_kernel(const int* __restrict__ i1p, const int* __restrict__ i2p,
                            int* __restrict__ cnt1, int* __restrict__ cnt2,
                            int N1, int N2) {
    int stride = gridDim.x * blockDim.x;
    int t = blockIdx.x * blockDim.x + threadIdx.x;
    for (int i = t; i < N1; i += stride) atomicAdd(&cnt1[i1p[i]], 1);
    for (int j = t; j < N2; j += stride) atomicAdd(&cnt2[i2p[j]], 1);
}

// ---------- K2: exclusive scan -> segment bounds + cursors (1 block) ----------
__global__ __launch_bounds__(1024) void scan_kernel(
    const int* __restrict__ cnt1, const int* __restrict__ cnt2,
    int* __restrict__ seg1, int* __restrict__ seg2,
    int* __restrict__ cur1, int* __restrict__ cur2, int S) {
    __shared__ int c1[1024], c2[1024];
    int tid = threadIdx.x;
    int n1 = 0, n2 = 0;
    if (tid < S) { n1 = cnt1[tid]; n2 = cnt2[tid]; c1[tid] = n1; c2[tid] = n2; }
    __syncthreads();
    for (int d = 1; d < S; d <<= 1) {
        int t1 = 0, t2 = 0;
        if (tid >= d && tid < S) { t1 = c1[tid - d]; t2 = c2[tid - d]; }
        __syncthreads();
        if (tid >= d && tid < S) { c1[tid] += t1; c2[tid] += t2; }
        __syncthreads();
    }
    if (tid < S) {
        seg1[tid + 1] = c1[tid]; seg2[tid + 1] = c2[tid];
        cur1[tid] = c1[tid] - n1; cur2[tid] = c2[tid] - n2;
        if (tid == 0) { seg1[0] = 0; seg2[0] = 0; }
    }
}

// ---------- K3: placement (sorted positions + packed reactants) ----------
__global__ void place_kernel(const int* __restrict__ i1r, const int* __restrict__ i1p,
                             const int* __restrict__ i2r, const int* __restrict__ i2p,
                             int* __restrict__ cur1, int* __restrict__ cur2,
                             unsigned short* __restrict__ pos1, unsigned short* __restrict__ rp1,
                             unsigned short* __restrict__ pos2, unsigned int* __restrict__ rp2,
                             int N1, int N2) {
    int stride = gridDim.x * blockDim.x;
    int t = blockIdx.x * blockDim.x + threadIdx.x;
    for (int i = t; i < N1; i += stride) {
        int p = atomicAdd(&cur1[i1p[i]], 1);
        pos1[i] = (unsigned short)p;           // coalesced write
        rp1[p]  = (unsigned short)i1r[i];      // scattered 2B write (tiny)
    }
    for (int j = t; j < N2; j += stride) {
        int p = atomicAdd(&cur2[i2p[j]], 1);
        pos2[j] = (unsigned short)p;
        rp2[p]  = (unsigned)i2r[2 * j] | ((unsigned)i2r[2 * j + 1] << 16);
    }
}

// ---------- Main kernel: specialized S=1024, N1=4096, N2=16384, BT=1024 ----------
__global__ __launch_bounds__(1024) void reaction_gather(
    const float* __restrict__ y_in, const float* __restrict__ rate_1,
    const float* __restrict__ rate_2,
    const int* __restrict__ seg1, const int* __restrict__ seg2,
    const unsigned short* __restrict__ pos1, const unsigned short* __restrict__ rp1,
    const unsigned short* __restrict__ pos2, const unsigned int* __restrict__ rp2,
    float* __restrict__ y_out) {
    // 156 KB static LDS (<= 160 KiB/CU): 1 block/CU, 16 waves.
    __shared__ float          y_s[1024];       //  4 KB
    __shared__ float          rate1_s[4096];   // 16 KB  (sorted order)
    __shared__ unsigned short rp1_s[4096];     //  8 KB  (sorted order)
    __shared__ float          rate2_s[16384];  // 64 KB  (sorted order)
    __shared__ unsigned int   rp2_s[16384];    // 64 KB  (sorted order)

    const int tid = threadIdx.x;
    const int b   = blockIdx.x;
    const float* __restrict__ yrow  = y_in  + (size_t)b * 1024;
    const float* __restrict__ r1row = rate_1 + (size_t)b * 4096;
    const float* __restrict__ r2row = rate_2 + (size_t)b * 16384;

    // ---- stage y row + phase-1 arrays ----
    y_s[tid] = yrow[tid];
    {
        int i = tid * 4;  // one iter covers N1=4096 with 1024 threads
        float4  r = *reinterpret_cast<const float4*>(r1row + i);
        ushort4 p = *reinterpret_cast<const ushort4*>(pos1 + i);
        rate1_s[p.x] = r.x; rate1_s[p.y] = r.y;   // scattered ds_write_b32 (~2-way, free)
        rate1_s[p.z] = r.z; rate1_s[p.w] = r.w;
    }
    // rp1 is already sorted -> straight coalesced copy (as u32)
    reinterpret_cast<unsigned*>(rp1_s)[tid]        = reinterpret_cast<const unsigned*>(rp1)[tid];
    reinterpret_cast<unsigned*>(rp1_s)[tid + 1024] = reinterpret_cast<const unsigned*>(rp1)[tid + 1024];

    // ---- issue phase-2 global loads into regs BEFORE phase-1 compute ----
    float4  r2v[4];
    ushort4 p2v[4];
    uint4   q2v[4];
#pragma unroll
    for (int c = 0; c < 4; ++c) {
        int i4 = c * 4096 + tid * 4;
        r2v[c] = *reinterpret_cast<const float4*>(r2row + i4);
        p2v[c] = *reinterpret_cast<const ushort4*>(pos2 + i4);
        q2v[c] = *reinterpret_cast<const uint4*>(rp2 + i4);
    }

    __syncthreads();  // phase-1 LDS ready

    // ---- phase-1 compute: thread owns slot `tid`, gathers its segment ----
    float acc = 0.f;
    {
        int s = seg1[tid], e = seg1[tid + 1];
#pragma unroll 2
        for (int k = s; k < e; ++k)
            acc += y_s[rp1_s[k]] * rate1_s[k];
    }

    // ---- write phase-2 arrays to LDS (loads have been in flight) ----
#pragma unroll
    for (int c = 0; c < 4; ++c) {
        int i4 = c * 4096 + tid * 4;
        rate2_s[p2v[c].x] = r2v[c].x;
        rate2_s[p2v[c].y] = r2v[c].y;
        rate2_s[p2v[c].z] = r2v[c].z;
        rate2_s[p2v[c].w] = r2v[c].w;
        *reinterpret_cast<uint4*>(&rp2_s[i4]) = q2v[c];  // straight copy, b128
    }
    __syncthreads();  // phase-2 LDS ready

    // ---- phase-2 compute ----
    {
        int s = seg2[tid], e = seg2[tid + 1];
#pragma unroll 2
        for (int k = s; k < e; ++k) {
            unsigned u = rp2_s[k];
            acc += y_s[u & 0xffffu] * y_s[u >> 16] * rate2_s[k];
        }
    }

    y_out[(size_t)b * 1024 + tid] = acc;  // coalesced
}

// ---------- Fallback (generic sizes): R2 atomic kernel ----------
template <int BLOCK>
__global__ __launch_bounds__(BLOCK) void reaction_fallback(
    const float* __restrict__ y_in, const float* __restrict__ rate_1,
    const float* __restrict__ rate_2, const int* __restrict__ inds_1r,
    const int* __restrict__ inds_1p, const int* __restrict__ inds_2r,
    const int* __restrict__ inds_2p, float* __restrict__ y_out,
    int S, int N1, int N2) {
    extern __shared__ float smem[];
    float* y_s = smem;
    float* acc = smem + S;
    const int b = blockIdx.x, tid = threadIdx.x;
    const float* yrow = y_in + (size_t)b * S;
    for (int i = tid; i < S; i += BLOCK) { y_s[i] = yrow[i]; acc[i] = 0.f; }
    __syncthreads();
    const float* r1 = rate_1 + (size_t)b * N1;
    for (int i = tid; i < N1; i += BLOCK)
        atomicAdd(&acc[inds_1p[i]], y_s[inds_1r[i]] * r1[i]);
    const float* r2 = rate_2 + (size_t)b * N2;
    for (int i = tid; i < N2; i += BLOCK)
        atomicAdd(&acc[inds_2p[i]], y_s[inds_2r[2 * i]] * y_s[inds_2r[2 * i + 1]] * r2[i]);
    __syncthreads();
    float* orow = y_out + (size_t)b * S;
    for (int i = tid; i < S; i += BLOCK) orow[i] = acc[i];
}

extern "C" void kernel_launch(void* const* d_in, const int* in_sizes, int n_in,
                              void* d_out, int out_size, void* d_ws, size_t ws_size,
                              hipStream_t stream) {
    const float* y_in    = (const float*)d_in[0];
    const float* rate_1  = (const float*)d_in[1];
    const float* rate_2  = (const float*)d_in[2];
    const int*   inds_1r = (const int*)d_in[3];
    const int*   inds_1p = (const int*)d_in[4];
    const int*   inds_2r = (const int*)d_in[5];
    const int*   inds_2p = (const int*)d_in[6];
    float*       y_out   = (float*)d_out;

    const int N1 = in_sizes[3];           // 4096
    const int N2 = in_sizes[6];           // 16384
    const int B  = in_sizes[1] / N1;      // 4096
    const int S  = in_sizes[0] / B;       // 1024

    const bool specialized = (S == 1024 && N1 == 4096 && N2 == 16384 &&
                              ws_size >= (size_t)(144 * 1024));
    if (!specialized) {
        size_t smem = (size_t)2 * S * sizeof(float);
        reaction_fallback<256><<<B, 256, smem, stream>>>(
            y_in, rate_1, rate_2, inds_1r, inds_1p, inds_2r, inds_2p,
            y_out, S, N1, N2);
        return;
    }

    // workspace layout (256B-aligned sections)
    char* ws = (char*)d_ws;
    int*            seg1 = (int*)(ws +       0);   // 1025 ints   (8 KB sec)
    int*            seg2 = (int*)(ws +  8 * 1024);
    int*            cnt1 = (int*)(ws + 16 * 1024); // 1024 ints
    int*            cnt2 = (int*)(ws + 20 * 1024);
    int*            cur1 = (int*)(ws + 24 * 1024);
    int*            cur2 = (int*)(ws + 28 * 1024);
    unsigned short* pos1 = (unsigned short*)(ws + 32 * 1024); // 4096 u16
    unsigned short* rp1  = (unsigned short*)(ws + 40 * 1024); // 4096 u16
    unsigned short* pos2 = (unsigned short*)(ws + 48 * 1024); // 16384 u16
    unsigned int*   rp2  = (unsigned int*)(ws + 80 * 1024);   // 16384 u32 -> ends at 144K

    hipMemsetAsync(cnt1, 0, 2 * 1024 * sizeof(int), stream);  // cnt1+cnt2 contiguous
    hist_kernel<<<80, 256, 0, stream>>>(inds_1p, inds_2p, cnt1, cnt2, N1, N2);
    scan_kernel<<<1, 1024, 0, stream>>>(cnt1, cnt2, seg1, seg2, cur1, cur2, S);
    place_kernel<<<80, 256, 0, stream>>>(inds_1r, inds_1p, inds_2r, inds_2p,
                                         cur1, cur2, pos1, rp1, pos2, rp2, N1, N2);
    reaction_gather<<<B, BT, 0, stream>>>(y_in, rate_1, rate_2,
                                          seg1, seg2, pos1, rp1, pos2, rp2, y_out);
}

// Round 4
// 145.171 us; speedup vs baseline: 3.1203x; 1.7213x over previous
//
#include <hip/hip_runtime.h>

// ReactionTerm, gather formulation v2.
// R3 lesson: pre-issuing 40 VGPRs of loads across a barrier spilled to scratch
// (+450 MB HBM), and segment-gather of sorted arrays had stride-16 bank
// conflicts. R4: rates stay in ORIGINAL order in LDS (linear copies only);
// the per-slot sort lives in a packed u32 payload (a | b<<10 | orig<<20),
// phase-2 split into 4 chunks of 4096 so orig fits 12 bits; payload array is
// PRE-SWIZZLED in global (SWZ(k)=k^((k>>5)&31)) so segment reads are
// bank-conflict-free while LDS staging stays linear. 68 KB LDS -> 2 blocks/CU.
//
// Geometry: B=4096, S=1024, N1=4096, N2=16384.

#define SWZ(k) ((k) ^ (((k) >> 5) & 31))

// ---------- K1: histogram (phase1 + 4 phase-2 chunks), global int atomics ----
__global__ void hist_kernel(const int* __restrict__ i1p, const int* __restrict__ i2p,
                            int* __restrict__ cnt, int N1, int N2) {
    int stride = gridDim.x * blockDim.x;
    int t = blockIdx.x * blockDim.x + threadIdx.x;
    for (int i = t; i < N1; i += stride) atomicAdd(&cnt[i1p[i]], 1);
    for (int j = t; j < N2; j += stride)
        atomicAdd(&cnt[1024 + (j >> 12) * 1024 + i2p[j]], 1);
}

// ---------- K2: 5 independent 1024-scans (block a = array a) ----------------
__global__ __launch_bounds__(1024) void scan_kernel(const int* __restrict__ cnt,
                                                    int* __restrict__ cur,
                                                    unsigned* __restrict__ segpack) {
    __shared__ int c_s[1024];
    const int tid = threadIdx.x;
    const int base = blockIdx.x * 1024;
    int n = cnt[base + tid];
    c_s[tid] = n;
    __syncthreads();
    for (int d = 1; d < 1024; d <<= 1) {
        int t = (tid >= d) ? c_s[tid - d] : 0;
        __syncthreads();
        if (tid >= d) c_s[tid] += t;
        __syncthreads();
    }
    int start = c_s[tid] - n;
    cur[base + tid] = start;
    segpack[base + tid] = (unsigned)start | ((unsigned)n << 16);
}

// ---------- K3: placement -> pre-swizzled packed payload --------------------
__global__ void place_kernel(const int* __restrict__ i1r, const int* __restrict__ i1p,
                             const int* __restrict__ i2r, const int* __restrict__ i2p,
                             int* __restrict__ cur,
                             unsigned* __restrict__ pk1, unsigned* __restrict__ pk2,
                             int N1, int N2) {
    int stride = gridDim.x * blockDim.x;
    int t = blockIdx.x * blockDim.x + threadIdx.x;
    for (int i = t; i < N1; i += stride) {
        int p = atomicAdd(&cur[i1p[i]], 1);
        pk1[SWZ(p)] = (unsigned)i1r[i] | ((unsigned)i << 10);        // a | j<<10
    }
    for (int j = t; j < N2; j += stride) {
        int c = j >> 12, jl = j & 4095;
        int p = atomicAdd(&cur[1024 + c * 1024 + i2p[j]], 1);
        pk2[c * 4096 + SWZ(p)] =
            (unsigned)i2r[2 * j] | ((unsigned)i2r[2 * j + 1] << 10) | ((unsigned)jl << 20);
    }
}

// ---------- Main kernel: S=1024, N1=4096, N2=16384, 1024 threads ------------
__global__ __launch_bounds__(1024) void reaction_gather(
    const float* __restrict__ y_in, const float* __restrict__ rate_1,
    const float* __restrict__ rate_2,
    const unsigned* __restrict__ segpack,
    const unsigned* __restrict__ pk1g, const unsigned* __restrict__ pk2g,
    float* __restrict__ y_out) {
    // 68 KB LDS -> 2 blocks/CU (32 waves).
    __shared__ __align__(16) float    y_s[1024];      //  4 KB
    __shared__ __align__(16) float    rate1_s[4096];  // 16 KB, ORIGINAL order
    __shared__ __align__(16) unsigned pk1_s[4096];    // 16 KB, sorted+swizzled
    __shared__ __align__(16) float    rate2_s[4096];  // 16 KB, chunk, orig order
    __shared__ __align__(16) unsigned pk2_s[4096];    // 16 KB, chunk payload

    const int tid = threadIdx.x, b = blockIdx.x;
    const float* __restrict__ yrow  = y_in   + (size_t)b * 1024;
    const float* __restrict__ r1row = rate_1 + (size_t)b * 4096;
    const float* __restrict__ r2row = rate_2 + (size_t)b * 16384;

    // Per-thread segment descriptors (5 u32 regs, L2-resident source).
    unsigned sp1 = segpack[tid];
    unsigned sp2[4];
#pragma unroll
    for (int c = 0; c < 4; ++c) sp2[c] = segpack[1024 + c * 1024 + tid];

    // Linear staging only: y row, phase-1 arrays, phase-2 chunk 0.
    y_s[tid] = yrow[tid];
    ((uint4*)rate1_s)[tid] = ((const uint4*)r1row)[tid];
    ((uint4*)pk1_s)[tid]   = ((const uint4*)pk1g)[tid];
    ((uint4*)rate2_s)[tid] = ((const uint4*)r2row)[tid];
    ((uint4*)pk2_s)[tid]   = ((const uint4*)pk2g)[tid];
    __syncthreads();

    float acc = 0.f;

    // Phase 1: thread owns slot tid, gathers its segment.
    {
        int s = (int)(sp1 & 0xffffu), e = s + (int)(sp1 >> 16);
        for (int k = s; k < e; ++k) {
            unsigned pk = pk1_s[SWZ(k)];
            acc += y_s[pk & 1023u] * rate1_s[pk >> 10];
        }
    }

    // Phase 2: 4 chunks of 4096 terms.
#pragma unroll
    for (int c = 0; c < 4; ++c) {
        if (c) {
            __syncthreads();  // previous chunk fully consumed
            ((uint4*)rate2_s)[tid] = ((const uint4*)(r2row + c * 4096))[tid];
            ((uint4*)pk2_s)[tid]   = ((const uint4*)(pk2g + c * 4096))[tid];
            __syncthreads();
        }
        int s = (int)(sp2[c] & 0xffffu), e = s + (int)(sp2[c] >> 16);
        for (int k = s; k < e; ++k) {
            unsigned pk = pk2_s[SWZ(k)];
            acc += y_s[pk & 1023u] * y_s[(pk >> 10) & 1023u] * rate2_s[pk >> 20];
        }
    }

    y_out[(size_t)b * 1024 + tid] = acc;  // coalesced
}

// ---------- Fallback (generic sizes) ----------------------------------------
template <int BLOCK>
__global__ __launch_bounds__(BLOCK) void reaction_fallback(
    const float* __restrict__ y_in, const float* __restrict__ rate_1,
    const float* __restrict__ rate_2, const int* __restrict__ inds_1r,
    const int* __restrict__ inds_1p, const int* __restrict__ inds_2r,
    const int* __restrict__ inds_2p, float* __restrict__ y_out,
    int S, int N1, int N2) {
    extern __shared__ float smem[];
    float* y_s = smem;
    float* acc = smem + S;
    const int b = blockIdx.x, tid = threadIdx.x;
    const float* yrow = y_in + (size_t)b * S;
    for (int i = tid; i < S; i += BLOCK) { y_s[i] = yrow[i]; acc[i] = 0.f; }
    __syncthreads();
    const float* r1 = rate_1 + (size_t)b * N1;
    for (int i = tid; i < N1; i += BLOCK)
        atomicAdd(&acc[inds_1p[i]], y_s[inds_1r[i]] * r1[i]);
    const float* r2 = rate_2 + (size_t)b * N2;
    for (int i = tid; i < N2; i += BLOCK)
        atomicAdd(&acc[inds_2p[i]], y_s[inds_2r[2 * i]] * y_s[inds_2r[2 * i + 1]] * r2[i]);
    __syncthreads();
    float* orow = y_out + (size_t)b * S;
    for (int i = tid; i < S; i += BLOCK) orow[i] = acc[i];
}

extern "C" void kernel_launch(void* const* d_in, const int* in_sizes, int n_in,
                              void* d_out, int out_size, void* d_ws, size_t ws_size,
                              hipStream_t stream) {
    const float* y_in    = (const float*)d_in[0];
    const float* rate_1  = (const float*)d_in[1];
    const float* rate_2  = (const float*)d_in[2];
    const int*   inds_1r = (const int*)d_in[3];
    const int*   inds_1p = (const int*)d_in[4];
    const int*   inds_2r = (const int*)d_in[5];
    const int*   inds_2p = (const int*)d_in[6];
    float*       y_out   = (float*)d_out;

    const int N1 = in_sizes[3];           // 4096
    const int N2 = in_sizes[6];           // 16384
    const int B  = in_sizes[1] / N1;      // 4096
    const int S  = in_sizes[0] / B;       // 1024

    const bool specialized = (S == 1024 && N1 == 4096 && N2 == 16384 &&
                              ws_size >= (size_t)(140 * 1024));
    if (!specialized) {
        size_t smem = (size_t)2 * S * sizeof(float);
        reaction_fallback<256><<<B, 256, smem, stream>>>(
            y_in, rate_1, rate_2, inds_1r, inds_1p, inds_2r, inds_2p,
            y_out, S, N1, N2);
        return;
    }

    // Workspace layout:
    //   cnt     : 5120 int  (phase1 + 4 chunks)   [ws +   0K, 20 KB]
    //   cur     : 5120 int                        [ws +  20K, 20 KB]
    //   segpack : 5120 u32  (start | cnt<<16)     [ws +  40K, 20 KB]
    //   pk1g    : 4096 u32                        [ws +  60K, 16 KB]
    //   pk2g    : 16384 u32 (4 chunks x 4096)     [ws +  76K, 64 KB] -> 140 KB
    char* ws = (char*)d_ws;
    int*      cnt     = (int*)(ws + 0);
    int*      cur     = (int*)(ws + 20 * 1024);
    unsigned* segpack = (unsigned*)(ws + 40 * 1024);
    unsigned* pk1g    = (unsigned*)(ws + 60 * 1024);
    unsigned* pk2g    = (unsigned*)(ws + 76 * 1024);

    hipMemsetAsync(cnt, 0, 5 * 1024 * sizeof(int), stream);
    hist_kernel<<<80, 256, 0, stream>>>(inds_1p, inds_2p, cnt, N1, N2);
    scan_kernel<<<5, 1024, 0, stream>>>(cnt, cur, segpack);
    place_kernel<<<80, 256, 0, stream>>>(inds_1r, inds_1p, inds_2r, inds_2p,
                                         cur, pk1g, pk2g, N1, N2);
    reaction_gather<<<B, 1024, 0, stream>>>(y_in, rate_1, rate_2,
                                            segpack, pk1g, pk2g, y_out);
}

// Round 5
// 131.786 us; speedup vs baseline: 3.4373x; 1.1016x over previous
//
#include <hip/hip_runtime.h>

// ReactionTerm, gather formulation v3.
// R4 lesson: the divergent segment loop did 4 LDS reads/term at wave-max
// segment length (~2.5x inflation). R5: products are computed in ORIGINAL
// term order (uniform work, rate straight from global registers, indices from
// L2) and written once to a sorted+swizzled LDS buffer; the divergent loop is
// reduced to 1 LDS read/term. Phase 2 uses one full 16384-sort (minimizes
// max-of-Poisson divergence). LDS 68 KB -> 2 blocks/CU.
//
// Geometry: B=4096, S=1024, N1=4096, N2=16384.

#define SWZ(k) ((k) ^ (((k) >> 5) & 31))

// ---------- K1: histogram of product slots ----------------------------------
__global__ void hist_kernel(const int* __restrict__ i1p, const int* __restrict__ i2p,
                            int* __restrict__ cnt, int N1, int N2) {
    int stride = gridDim.x * blockDim.x;
    int t = blockIdx.x * blockDim.x + threadIdx.x;
    for (int i = t; i < N1; i += stride) atomicAdd(&cnt[i1p[i]], 1);
    for (int j = t; j < N2; j += stride) atomicAdd(&cnt[1024 + i2p[j]], 1);
}

// ---------- K2: two independent 1024-scans (block = array) ------------------
__global__ __launch_bounds__(1024) void scan_kernel(const int* __restrict__ cnt,
                                                    int* __restrict__ cur,
                                                    unsigned* __restrict__ segpack) {
    __shared__ int c_s[1024];
    const int tid = threadIdx.x;
    const int base = blockIdx.x * 1024;
    int n = cnt[base + tid];
    c_s[tid] = n;
    __syncthreads();
    for (int d = 1; d < 1024; d <<= 1) {
        int t = (tid >= d) ? c_s[tid - d] : 0;
        __syncthreads();
        if (tid >= d) c_s[tid] += t;
        __syncthreads();
    }
    int start = c_s[tid] - n;
    cur[base + tid] = start;
    // phase1: start|cnt<<16 (start<4096); phase2: start|cnt<<20 (start<16384)
    segpack[base + tid] = (blockIdx.x == 0)
        ? ((unsigned)start | ((unsigned)n << 16))
        : ((unsigned)start | ((unsigned)n << 20));
}

// ---------- K3: placement -> sorted position of each term (original order) --
__global__ void place_kernel(const int* __restrict__ i1p, const int* __restrict__ i2p,
                             int* __restrict__ cur,
                             unsigned short* __restrict__ pos1,
                             unsigned short* __restrict__ pos2, int N1, int N2) {
    int stride = gridDim.x * blockDim.x;
    int t = blockIdx.x * blockDim.x + threadIdx.x;
    for (int i = t; i < N1; i += stride)
        pos1[i] = (unsigned short)atomicAdd(&cur[i1p[i]], 1);
    for (int j = t; j < N2; j += stride)
        pos2[j] = (unsigned short)atomicAdd(&cur[1024 + i2p[j]], 1);
}

// ---------- Main kernel: S=1024, N1=4096, N2=16384, 1024 threads ------------
__global__ __launch_bounds__(1024) void reaction_gather(
    const float* __restrict__ y_in, const float* __restrict__ rate_1,
    const float* __restrict__ rate_2,
    const int* __restrict__ i1r, const int* __restrict__ i2r,
    const unsigned short* __restrict__ pos1, const unsigned short* __restrict__ pos2,
    const unsigned* __restrict__ segpack,
    float* __restrict__ y_out) {
    __shared__ __align__(16) float y_s[1024];    //  4 KB
    __shared__ __align__(16) float buf[16384];   // 64 KB sorted-product buffer

    const int tid = threadIdx.x, b = blockIdx.x;

    y_s[tid] = y_in[(size_t)b * 1024 + tid];
    const unsigned s1 = segpack[tid];
    const unsigned s2 = segpack[1024 + tid];
    __syncthreads();  // y_s ready

    // ---- Phase 1 products (uniform, original order) ----
    {
        int4    ia = ((const int4*)i1r)[tid];
        float4  r  = ((const float4*)(rate_1 + (size_t)b * 4096))[tid];
        ushort4 p  = ((const ushort4*)pos1)[tid];
        buf[SWZ((int)p.x)] = y_s[ia.x] * r.x;
        buf[SWZ((int)p.y)] = y_s[ia.y] * r.y;
        buf[SWZ((int)p.z)] = y_s[ia.z] * r.z;
        buf[SWZ((int)p.w)] = y_s[ia.w] * r.w;
    }
    __syncthreads();

    // ---- Phase 1 segment sum (1 LDS read/term) ----
    float acc = 0.f;
    {
        int s = (int)(s1 & 0xffffu), n = (int)(s1 >> 16);
        for (int k = s; k < s + n; ++k) acc += buf[SWZ(k)];
    }
    __syncthreads();  // buf fully consumed

    // ---- Phase 2 products (uniform, original order, full 16384 sort) ----
    const float* __restrict__ r2row = rate_2 + (size_t)b * 16384;
#pragma unroll 2
    for (int g = 0; g < 4; ++g) {
        int4    e0 = ((const int4*)i2r)[g * 2048 + tid * 2];      // terms 4t..4t+1
        int4    e1 = ((const int4*)i2r)[g * 2048 + tid * 2 + 1];  // terms 4t+2..4t+3
        float4  r  = ((const float4*)r2row)[g * 1024 + tid];
        ushort4 p  = ((const ushort4*)pos2)[g * 1024 + tid];
        buf[SWZ((int)p.x)] = y_s[e0.x] * y_s[e0.y] * r.x;
        buf[SWZ((int)p.y)] = y_s[e0.z] * y_s[e0.w] * r.y;
        buf[SWZ((int)p.z)] = y_s[e1.x] * y_s[e1.y] * r.z;
        buf[SWZ((int)p.w)] = y_s[e1.z] * y_s[e1.w] * r.w;
    }
    __syncthreads();

    // ---- Phase 2 segment sum ----
    {
        int s = (int)(s2 & 0xfffffu), n = (int)(s2 >> 20);
        for (int k = s; k < s + n; ++k) acc += buf[SWZ(k)];
    }

    y_out[(size_t)b * 1024 + tid] = acc;  // coalesced
}

// ---------- Fallback (generic sizes) ----------------------------------------
template <int BLOCK>
__global__ __launch_bounds__(BLOCK) void reaction_fallback(
    const float* __restrict__ y_in, const float* __restrict__ rate_1,
    const float* __restrict__ rate_2, const int* __restrict__ inds_1r,
    const int* __restrict__ inds_1p, const int* __restrict__ inds_2r,
    const int* __restrict__ inds_2p, float* __restrict__ y_out,
    int S, int N1, int N2) {
    extern __shared__ float smem[];
    float* y_s = smem;
    float* acc = smem + S;
    const int b = blockIdx.x, tid = threadIdx.x;
    const float* yrow = y_in + (size_t)b * S;
    for (int i = tid; i < S; i += BLOCK) { y_s[i] = yrow[i]; acc[i] = 0.f; }
    __syncthreads();
    const float* r1 = rate_1 + (size_t)b * N1;
    for (int i = tid; i < N1; i += BLOCK)
        atomicAdd(&acc[inds_1p[i]], y_s[inds_1r[i]] * r1[i]);
    const float* r2 = rate_2 + (size_t)b * N2;
    for (int i = tid; i < N2; i += BLOCK)
        atomicAdd(&acc[inds_2p[i]], y_s[inds_2r[2 * i]] * y_s[inds_2r[2 * i + 1]] * r2[i]);
    __syncthreads();
    float* orow = y_out + (size_t)b * S;
    for (int i = tid; i < S; i += BLOCK) orow[i] = acc[i];
}

extern "C" void kernel_launch(void* const* d_in, const int* in_sizes, int n_in,
                              void* d_out, int out_size, void* d_ws, size_t ws_size,
                              hipStream_t stream) {
    const float* y_in    = (const float*)d_in[0];
    const float* rate_1  = (const float*)d_in[1];
    const float* rate_2  = (const float*)d_in[2];
    const int*   inds_1r = (const int*)d_in[3];
    const int*   inds_1p = (const int*)d_in[4];
    const int*   inds_2r = (const int*)d_in[5];
    const int*   inds_2p = (const int*)d_in[6];
    float*       y_out   = (float*)d_out;

    const int N1 = in_sizes[3];           // 4096
    const int N2 = in_sizes[6];           // 16384
    const int B  = in_sizes[1] / N1;      // 4096
    const int S  = in_sizes[0] / B;       // 1024

    const bool specialized = (S == 1024 && N1 == 4096 && N2 == 16384 &&
                              ws_size >= (size_t)(64 * 1024));
    if (!specialized) {
        size_t smem = (size_t)2 * S * sizeof(float);
        reaction_fallback<256><<<B, 256, smem, stream>>>(
            y_in, rate_1, rate_2, inds_1r, inds_1p, inds_2r, inds_2p,
            y_out, S, N1, N2);
        return;
    }

    // Workspace:
    //   cnt     : 2048 int   [ 0K,  8K)   (phase1 slots | phase2 slots)
    //   cur     : 2048 int   [ 8K, 16K)
    //   segpack : 2048 u32   [16K, 24K)   (start|cnt packed)
    //   pos1    : 4096 u16   [24K, 32K)
    //   pos2    : 16384 u16  [32K, 64K)
    char* ws = (char*)d_ws;
    int*            cnt     = (int*)(ws + 0);
    int*            cur     = (int*)(ws + 8 * 1024);
    unsigned*       segpack = (unsigned*)(ws + 16 * 1024);
    unsigned short* pos1    = (unsigned short*)(ws + 24 * 1024);
    unsigned short* pos2    = (unsigned short*)(ws + 32 * 1024);

    hipMemsetAsync(cnt, 0, 2048 * sizeof(int), stream);
    hist_kernel<<<80, 256, 0, stream>>>(inds_1p, inds_2p, cnt, N1, N2);
    scan_kernel<<<2, 1024, 0, stream>>>(cnt, cur, segpack);
    place_kernel<<<80, 256, 0, stream>>>(inds_1p, inds_2p, cur, pos1, pos2, N1, N2);
    reaction_gather<<<B, 1024, 0, stream>>>(y_in, rate_1, rate_2,
                                            inds_1r, inds_2r, pos1, pos2,
                                            segpack, y_out);
}

// Round 6
// 127.499 us; speedup vs baseline: 3.5529x; 1.0336x over previous
//
#include <hip/hip_runtime.h>

// ReactionTerm, gather formulation v4.
// R5 lesson: SWZ forced scalar b32 segment reads + per-access XOR VALU; LDS
// instr count (~96/wave) made the LDS pipe the bottleneck. R6: no swizzle;
// scan pads each slot's segment to EVEN length (pad slot zeroed by owner), so
// segment sums are ds_read_b64 loops; scattered product writes are random
// (~2-way, free). Setup collapsed to ONE kernel (grid=2, LDS histogram+scan+
// place per phase). LDS 72 KB -> 2 blocks/CU.
//
// Geometry: B=4096, S=1024, N1=4096, N2=16384.

// ---------- setup: block 0 = phase 1, block 1 = phase 2 ----------------------
__global__ __launch_bounds__(1024) void setup_kernel(
    const int* __restrict__ i1p, const int* __restrict__ i2p,
    unsigned short* __restrict__ pos1, unsigned short* __restrict__ pos2,
    unsigned* __restrict__ segpack) {
    __shared__ int h[1024];
    __shared__ int c[1024];
    const int tid = threadIdx.x;
    const int ph  = blockIdx.x;              // 0: first-order, 1: second-order
    const int per = ph ? 16 : 4;             // terms per thread
    const int* __restrict__ ip = ph ? i2p : i1p;
    unsigned short* __restrict__ pos = ph ? pos2 : pos1;

    h[tid] = 0;
    __syncthreads();
    for (int j = 0; j < per; ++j)
        atomicAdd(&h[ip[j * 1024 + tid]], 1);          // native ds_add_u32
    __syncthreads();

    int n  = h[tid];
    int pn = n + (n & 1);                              // pad to even
    c[tid] = pn;
    __syncthreads();
    for (int d = 1; d < 1024; d <<= 1) {
        int t = (tid >= d) ? c[tid - d] : 0;
        __syncthreads();
        if (tid >= d) c[tid] += t;
        __syncthreads();
    }
    int start = c[tid] - pn;                           // padded exclusive scan
    segpack[ph * 1024 + tid] = (unsigned)start | ((unsigned)n << 16);
    __syncthreads();
    c[tid] = start;                                    // reuse as cursor
    __syncthreads();
    for (int j = 0; j < per; ++j) {
        int idx = j * 1024 + tid;
        int p = atomicAdd(&c[ip[idx]], 1);             // ds_add_rtn_u32
        pos[idx] = (unsigned short)p;
    }
}

// ---------- main kernel: S=1024, N1=4096, N2=16384, 1024 threads -------------
__global__ __launch_bounds__(1024) void reaction_gather(
    const float* __restrict__ y_in, const float* __restrict__ rate_1,
    const float* __restrict__ rate_2,
    const int* __restrict__ i1r, const int* __restrict__ i2r,
    const unsigned short* __restrict__ pos1, const unsigned short* __restrict__ pos2,
    const unsigned* __restrict__ segpack,
    float* __restrict__ y_out) {
    __shared__ __align__(16) float y_s[1024];    //  4 KB
    __shared__ __align__(16) float buf[17408];   // 68 KB (16384 + up to 1024 pads)

    const int tid = threadIdx.x, b = blockIdx.x;

    y_s[tid] = y_in[(size_t)b * 1024 + tid];
    const unsigned sp1 = segpack[tid];
    const unsigned sp2 = segpack[1024 + tid];
    const int s1 = (int)(sp1 & 0xffffu), n1 = (int)(sp1 >> 16);
    const int s2 = (int)(sp2 & 0xffffu), n2 = (int)(sp2 >> 16);
    __syncthreads();

    // ---- Phase 1 products (uniform, original order) + own pad zero ----
    {
        int4    ia = ((const int4*)i1r)[tid];
        float4  r  = ((const float4*)(rate_1 + (size_t)b * 4096))[tid];
        ushort4 p  = ((const ushort4*)pos1)[tid];
        buf[p.x] = y_s[ia.x] * r.x;
        buf[p.y] = y_s[ia.y] * r.y;
        buf[p.z] = y_s[ia.z] * r.z;
        buf[p.w] = y_s[ia.w] * r.w;
        if (n1 & 1) buf[s1 + n1] = 0.f;
    }
    __syncthreads();

    // ---- Phase 1 segment sum: 2-aligned, ds_read_b64 ----
    float acc = 0.f;
    for (int k = s1; k < s1 + n1; k += 2) {
        float2 v = *(const float2*)&buf[k];
        acc += v.x + v.y;
    }
    __syncthreads();  // buf fully consumed

    // ---- Phase 2 products (uniform, original order) + own pad zero ----
    const float* __restrict__ r2row = rate_2 + (size_t)b * 16384;
    if (n2 & 1) buf[s2 + n2] = 0.f;
#pragma unroll
    for (int g = 0; g < 4; ++g) {
        int4    e0 = ((const int4*)i2r)[g * 2048 + tid * 2];      // terms 4t,4t+1
        int4    e1 = ((const int4*)i2r)[g * 2048 + tid * 2 + 1];  // terms 4t+2,4t+3
        float4  r  = ((const float4*)r2row)[g * 1024 + tid];
        ushort4 p  = ((const ushort4*)pos2)[g * 1024 + tid];
        buf[p.x] = y_s[e0.x] * y_s[e0.y] * r.x;
        buf[p.y] = y_s[e0.z] * y_s[e0.w] * r.y;
        buf[p.z] = y_s[e1.x] * y_s[e1.y] * r.z;
        buf[p.w] = y_s[e1.z] * y_s[e1.w] * r.w;
    }
    __syncthreads();

    // ---- Phase 2 segment sum ----
    for (int k = s2; k < s2 + n2; k += 2) {
        float2 v = *(const float2*)&buf[k];
        acc += v.x + v.y;
    }

    y_out[(size_t)b * 1024 + tid] = acc;  // coalesced
}

// ---------- Fallback (generic sizes) ------------------------------------------
template <int BLOCK>
__global__ __launch_bounds__(BLOCK) void reaction_fallback(
    const float* __restrict__ y_in, const float* __restrict__ rate_1,
    const float* __restrict__ rate_2, const int* __restrict__ inds_1r,
    const int* __restrict__ inds_1p, const int* __restrict__ inds_2r,
    const int* __restrict__ inds_2p, float* __restrict__ y_out,
    int S, int N1, int N2) {
    extern __shared__ float smem[];
    float* y_s = smem;
    float* acc = smem + S;
    const int b = blockIdx.x, tid = threadIdx.x;
    const float* yrow = y_in + (size_t)b * S;
    for (int i = tid; i < S; i += BLOCK) { y_s[i] = yrow[i]; acc[i] = 0.f; }
    __syncthreads();
    const float* r1 = rate_1 + (size_t)b * N1;
    for (int i = tid; i < N1; i += BLOCK)
        atomicAdd(&acc[inds_1p[i]], y_s[inds_1r[i]] * r1[i]);
    const float* r2 = rate_2 + (size_t)b * N2;
    for (int i = tid; i < N2; i += BLOCK)
        atomicAdd(&acc[inds_2p[i]], y_s[inds_2r[2 * i]] * y_s[inds_2r[2 * i + 1]] * r2[i]);
    __syncthreads();
    float* orow = y_out + (size_t)b * S;
    for (int i = tid; i < S; i += BLOCK) orow[i] = acc[i];
}

extern "C" void kernel_launch(void* const* d_in, const int* in_sizes, int n_in,
                              void* d_out, int out_size, void* d_ws, size_t ws_size,
                              hipStream_t stream) {
    const float* y_in    = (const float*)d_in[0];
    const float* rate_1  = (const float*)d_in[1];
    const float* rate_2  = (const float*)d_in[2];
    const int*   inds_1r = (const int*)d_in[3];
    const int*   inds_1p = (const int*)d_in[4];
    const int*   inds_2r = (const int*)d_in[5];
    const int*   inds_2p = (const int*)d_in[6];
    float*       y_out   = (float*)d_out;

    const int N1 = in_sizes[3];           // 4096
    const int N2 = in_sizes[6];           // 16384
    const int B  = in_sizes[1] / N1;      // 4096
    const int S  = in_sizes[0] / B;       // 1024

    const bool specialized = (S == 1024 && N1 == 4096 && N2 == 16384 &&
                              ws_size >= (size_t)(48 * 1024));
    if (!specialized) {
        size_t smem = (size_t)2 * S * sizeof(float);
        reaction_fallback<256><<<B, 256, smem, stream>>>(
            y_in, rate_1, rate_2, inds_1r, inds_1p, inds_2r, inds_2p,
            y_out, S, N1, N2);
        return;
    }

    // Workspace:
    //   segpack : 2048 u32  [ 0K,  8K)   (start | n<<16, padded-scan starts)
    //   pos1    : 4096 u16  [ 8K, 16K)
    //   pos2    : 16384 u16 [16K, 48K)
    char* ws = (char*)d_ws;
    unsigned*       segpack = (unsigned*)(ws + 0);
    unsigned short* pos1    = (unsigned short*)(ws + 8 * 1024);
    unsigned short* pos2    = (unsigned short*)(ws + 16 * 1024);

    setup_kernel<<<2, 1024, 0, stream>>>(inds_1p, inds_2p, pos1, pos2, segpack);
    reaction_gather<<<B, 1024, 0, stream>>>(y_in, rate_1, rate_2,
                                            inds_1r, inds_2r, pos1, pos2,
                                            segpack, y_out);
}

// Round 7
// 80.839 us; speedup vs baseline: 5.6036x; 1.5772x over previous
//
#include <hip/hip_runtime.h>

// ReactionTerm v5: 4-row batching -> all LDS traffic is b128.
// R6 lesson: bottleneck is LDS instruction count/row (~76 b32-ish instrs,
// random-gather conflicts). Indices are row-invariant, so a block handles 4
// batch rows; y_s/buf become float4 (one row per component): y-gather,
// product scatter, and segment sum are single ds_*_b128 per term carrying 4
// rows. Positions pre-swizzled SWL(p)=p^((p>>3)&7) to kill the stride-64B
// 2-quad pathology in sequential segment reads. Phase 2 in 4 chunks of 4096.
// LDS 80 KB (buf 64 + y_s 16). Geometry: B=4096, S=1024, N1=4096, N2=16384.

#define SWL(k) ((k) ^ (((k) >> 3) & 7))

// ---------- setup: 5 blocks (0: phase1; 1..4: phase2 chunk) ------------------
__global__ __launch_bounds__(1024) void setup_kernel(
    const int* __restrict__ i1p, const int* __restrict__ i2p,
    unsigned short* __restrict__ pos1, unsigned short* __restrict__ pos2,
    unsigned* __restrict__ segpack) {
    __shared__ int h[1024];
    __shared__ int c[1024];
    const int tid = threadIdx.x;
    const int ph  = blockIdx.x;  // 0: first-order; 1..4: second-order chunk ph-1
    const int* __restrict__ ip = (ph == 0) ? i1p : (i2p + (ph - 1) * 4096);
    unsigned short* __restrict__ pos = (ph == 0) ? pos1 : (pos2 + (ph - 1) * 4096);

    h[tid] = 0;
    __syncthreads();
#pragma unroll
    for (int j = 0; j < 4; ++j) atomicAdd(&h[ip[j * 1024 + tid]], 1);
    __syncthreads();
    int n = h[tid];
    c[tid] = n;
    __syncthreads();
    for (int d = 1; d < 1024; d <<= 1) {
        int t = (tid >= d) ? c[tid - d] : 0;
        __syncthreads();
        if (tid >= d) c[tid] += t;
        __syncthreads();
    }
    int start = c[tid] - n;  // exclusive scan
    segpack[ph * 1024 + tid] = (unsigned)start | ((unsigned)n << 16);
    __syncthreads();
    c[tid] = start;          // reuse as cursor
    __syncthreads();
#pragma unroll
    for (int j = 0; j < 4; ++j) {
        int idx = j * 1024 + tid;
        int p = atomicAdd(&c[ip[idx]], 1);           // ds_add_rtn_u32
        pos[idx] = (unsigned short)SWL(p);           // swizzle baked in
    }
}

// ---------- main: 4 rows/block, 1024 threads ---------------------------------
__global__ __launch_bounds__(1024, 4) void reaction_gather4(
    const float* __restrict__ y_in, const float* __restrict__ rate_1,
    const float* __restrict__ rate_2,
    const int* __restrict__ i1r, const int* __restrict__ i2r,
    const unsigned short* __restrict__ pos1, const unsigned short* __restrict__ pos2,
    const unsigned* __restrict__ segpack,
    float* __restrict__ y_out) {
    __shared__ float4 y_s[1024];  // 16 KB: y_s[idx] = rows b0..b0+3 at idx
    __shared__ float4 buf[4096];  // 64 KB: swizzled sorted products, 4 rows

    const int tid = threadIdx.x;
    const long b0 = (long)blockIdx.x * 4;

    // stage 4 y rows (coalesced per row)
    {
        float v0 = y_in[(b0 + 0) * 1024 + tid];
        float v1 = y_in[(b0 + 1) * 1024 + tid];
        float v2 = y_in[(b0 + 2) * 1024 + tid];
        float v3 = y_in[(b0 + 3) * 1024 + tid];
        y_s[tid] = make_float4(v0, v1, v2, v3);
    }
    __syncthreads();

    float4 acc = make_float4(0.f, 0.f, 0.f, 0.f);

    // ---- phase 1: 4096 terms ----
    {
        int4    ia = ((const int4*)i1r)[tid];
        ushort4 p  = ((const ushort4*)pos1)[tid];
        const float* r1b = rate_1 + b0 * 4096;
        float4 q0 = ((const float4*)(r1b        ))[tid];
        float4 q1 = ((const float4*)(r1b +  4096))[tid];
        float4 q2 = ((const float4*)(r1b +  8192))[tid];
        float4 q3 = ((const float4*)(r1b + 12288))[tid];
        float4 y;
        y = y_s[ia.x]; buf[p.x] = make_float4(y.x*q0.x, y.y*q1.x, y.z*q2.x, y.w*q3.x);
        y = y_s[ia.y]; buf[p.y] = make_float4(y.x*q0.y, y.y*q1.y, y.z*q2.y, y.w*q3.y);
        y = y_s[ia.z]; buf[p.z] = make_float4(y.x*q0.z, y.y*q1.z, y.z*q2.z, y.w*q3.z);
        y = y_s[ia.w]; buf[p.w] = make_float4(y.x*q0.w, y.y*q1.w, y.z*q2.w, y.w*q3.w);
    }
    __syncthreads();
    {
        unsigned sp = segpack[tid];
        int s = (int)(sp & 0xffffu), e = s + (int)(sp >> 16);
        for (int k = s; k < e; ++k) {
            float4 v = buf[SWL(k)];
            acc.x += v.x; acc.y += v.y; acc.z += v.z; acc.w += v.w;
        }
    }
    __syncthreads();  // buf consumed

    // ---- phase 2: 4 chunks of 4096 terms ----
    const int4* __restrict__ i2r4 = (const int4*)i2r;
    const float* __restrict__ r2b = rate_2 + b0 * 16384;
#pragma unroll 1
    for (int c = 0; c < 4; ++c) {
        const int cb = c * 4096;
        int4    e0 = i2r4[cb / 2 + 2 * tid];      // terms t0,t1
        int4    e1 = i2r4[cb / 2 + 2 * tid + 1];  // terms t2,t3
        ushort4 p  = ((const ushort4*)(pos2 + cb))[tid];
        float4  q0 = ((const float4*)(r2b + cb        ))[tid];
        float4  q1 = ((const float4*)(r2b + cb + 16384))[tid];
        float4  q2 = ((const float4*)(r2b + cb + 32768))[tid];
        float4  q3 = ((const float4*)(r2b + cb + 49152))[tid];
        float4 ya, yb;
        ya = y_s[e0.x]; yb = y_s[e0.y];
        buf[p.x] = make_float4(ya.x*yb.x*q0.x, ya.y*yb.y*q1.x, ya.z*yb.z*q2.x, ya.w*yb.w*q3.x);
        ya = y_s[e0.z]; yb = y_s[e0.w];
        buf[p.y] = make_float4(ya.x*yb.x*q0.y, ya.y*yb.y*q1.y, ya.z*yb.z*q2.y, ya.w*yb.w*q3.y);
        ya = y_s[e1.x]; yb = y_s[e1.y];
        buf[p.z] = make_float4(ya.x*yb.x*q0.z, ya.y*yb.y*q1.z, ya.z*yb.z*q2.z, ya.w*yb.w*q3.z);
        ya = y_s[e1.z]; yb = y_s[e1.w];
        buf[p.w] = make_float4(ya.x*yb.x*q0.w, ya.y*yb.y*q1.w, ya.z*yb.z*q2.w, ya.w*yb.w*q3.w);
        __syncthreads();
        unsigned sp = segpack[(1 + c) * 1024 + tid];
        int s = (int)(sp & 0xffffu), e = s + (int)(sp >> 16);
        for (int k = s; k < e; ++k) {
            float4 v = buf[SWL(k)];
            acc.x += v.x; acc.y += v.y; acc.z += v.z; acc.w += v.w;
        }
        __syncthreads();  // buf consumed before next chunk overwrites
    }

    y_out[(b0 + 0) * 1024 + tid] = acc.x;
    y_out[(b0 + 1) * 1024 + tid] = acc.y;
    y_out[(b0 + 2) * 1024 + tid] = acc.z;
    y_out[(b0 + 3) * 1024 + tid] = acc.w;
}

// ---------- Fallback (generic sizes) ------------------------------------------
template <int BLOCK>
__global__ __launch_bounds__(BLOCK) void reaction_fallback(
    const float* __restrict__ y_in, const float* __restrict__ rate_1,
    const float* __restrict__ rate_2, const int* __restrict__ inds_1r,
    const int* __restrict__ inds_1p, const int* __restrict__ inds_2r,
    const int* __restrict__ inds_2p, float* __restrict__ y_out,
    int S, int N1, int N2) {
    extern __shared__ float smem[];
    float* y_s = smem;
    float* acc = smem + S;
    const int b = blockIdx.x, tid = threadIdx.x;
    const float* yrow = y_in + (size_t)b * S;
    for (int i = tid; i < S; i += BLOCK) { y_s[i] = yrow[i]; acc[i] = 0.f; }
    __syncthreads();
    const float* r1 = rate_1 + (size_t)b * N1;
    for (int i = tid; i < N1; i += BLOCK)
        atomicAdd(&acc[inds_1p[i]], y_s[inds_1r[i]] * r1[i]);
    const float* r2 = rate_2 + (size_t)b * N2;
    for (int i = tid; i < N2; i += BLOCK)
        atomicAdd(&acc[inds_2p[i]], y_s[inds_2r[2 * i]] * y_s[inds_2r[2 * i + 1]] * r2[i]);
    __syncthreads();
    float* orow = y_out + (size_t)b * S;
    for (int i = tid; i < S; i += BLOCK) orow[i] = acc[i];
}

extern "C" void kernel_launch(void* const* d_in, const int* in_sizes, int n_in,
                              void* d_out, int out_size, void* d_ws, size_t ws_size,
                              hipStream_t stream) {
    const float* y_in    = (const float*)d_in[0];
    const float* rate_1  = (const float*)d_in[1];
    const float* rate_2  = (const float*)d_in[2];
    const int*   inds_1r = (const int*)d_in[3];
    const int*   inds_1p = (const int*)d_in[4];
    const int*   inds_2r = (const int*)d_in[5];
    const int*   inds_2p = (const int*)d_in[6];
    float*       y_out   = (float*)d_out;

    const int N1 = in_sizes[3];           // 4096
    const int N2 = in_sizes[6];           // 16384
    const int B  = in_sizes[1] / N1;      // 4096
    const int S  = in_sizes[0] / B;       // 1024

    const bool specialized = (S == 1024 && N1 == 4096 && N2 == 16384 &&
                              (B % 4) == 0 && ws_size >= (size_t)(60 * 1024));
    if (!specialized) {
        size_t smem = (size_t)2 * S * sizeof(float);
        reaction_fallback<256><<<B, 256, smem, stream>>>(
            y_in, rate_1, rate_2, inds_1r, inds_1p, inds_2r, inds_2p,
            y_out, S, N1, N2);
        return;
    }

    // Workspace:
    //   segpack : 5120 u32  [ 0K, 20K)  (ph1 + 4 ph2 chunks; start | n<<16)
    //   pos1    : 4096 u16  [20K, 28K)  (swizzled positions)
    //   pos2    : 16384 u16 [28K, 60K)  (chunk-local swizzled positions)
    char* ws = (char*)d_ws;
    unsigned*       segpack = (unsigned*)(ws + 0);
    unsigned short* pos1    = (unsigned short*)(ws + 20 * 1024);
    unsigned short* pos2    = (unsigned short*)(ws + 28 * 1024);

    setup_kernel<<<5, 1024, 0, stream>>>(inds_1p, inds_2p, pos1, pos2, segpack);
    reaction_gather4<<<B / 4, 1024, 0, stream>>>(y_in, rate_1, rate_2,
                                                 inds_1r, inds_2r, pos1, pos2,
                                                 segpack, y_out);
}